// Round 6
// baseline (922.767 us; speedup 1.0000x reference)
//
#include <hip/hip_runtime.h>
#include <hip/hip_bf16.h>

typedef unsigned short u16;
typedef unsigned int u32;
typedef __bf16 bf16x8 __attribute__((ext_vector_type(8)));
typedef float f32x4 __attribute__((ext_vector_type(4)));

// output element offsets (f32 elements)
#define OUT_POOLED 0
#define OUT_MEM    6291456
#define OUT_STATE  56623104
#define OUT_HOLD   65011712
#define OUT_ROUTE  65208320

#define SW(r) (((r)&7)<<4)

__device__ __forceinline__ float b2f(u16 u){ u32 v=((u32)u)<<16; float f; __builtin_memcpy(&f,&v,4); return f; }
__device__ __forceinline__ u16 f2b(float f){ __hip_bfloat16 h=__float2bfloat16(f); u16 r; __builtin_memcpy(&r,&h,2); return r; }
__device__ __forceinline__ float sigf(float x){ return __builtin_amdgcn_rcpf(1.0f+__builtin_amdgcn_exp2f(-1.4426950408889634f*x)); }
__device__ __forceinline__ float tanh_(float x){ return 1.0f-2.0f*__builtin_amdgcn_rcpf(1.0f+__builtin_amdgcn_exp2f(2.8853900817779268f*x)); }
__device__ __forceinline__ float geluf(float x){
  float z = 0.7071067811865476f*x;
  float az = __builtin_fabsf(z);
  float t = __builtin_amdgcn_rcpf(1.0f+0.3275911f*az);
  float p = t*(0.254829592f+t*(-0.284496736f+t*(1.421413741f+t*(-1.453152027f+t*1.061405429f))));
  float e = __builtin_amdgcn_exp2f(-1.4426950408889634f*az*az);
  float er = 1.0f-p*e;
  er = (z<0.0f)? -er : er;
  return 0.5f*x*(1.0f+er);
}

// ---------------- prep: wcat pack, bcat, b_comb, + bf16 weight packs (wib2/wihb/wmT) ----------------
__global__ void k_prep(const float* __restrict__ Ws, const float* __restrict__ bs,
                       const float* __restrict__ bm, const float* __restrict__ Wm,
                       const float* __restrict__ Wh1, const float* __restrict__ bh1,
                       const float* __restrict__ Wt1, const float* __restrict__ bt1,
                       const float* __restrict__ Wv1, const float* __restrict__ bv1,
                       const float* __restrict__ Wi, const float* __restrict__ ek,
                       const float* __restrict__ Wih,
                       u16* __restrict__ wcat, float* __restrict__ bcat, float* __restrict__ bcomb,
                       u16* __restrict__ wib2, u16* __restrict__ wihb, u16* __restrict__ wmT)
{
  __shared__ float bmS[768];
  int tid = threadIdx.x;
  for(int i=tid;i<768;i+=256) bmS[i]=bm[i];
  __syncthreads();
  // bcomb: one wave per d
  {
    int w = tid>>6, lane = tid&63;
    int d = blockIdx.x*4 + w;
    float acc=0.f;
    for(int e=0;e<8;e++){
      const float* row = Ws + (size_t)d*6144 + e*768;
      #pragma unroll
      for(int it=0; it<3; it++){
        int c = it*256 + lane*4;
        float4 u = *reinterpret_cast<const float4*>(row + c);
        acc += u.x*bmS[c]+u.y*bmS[c+1]+u.z*bmS[c+2]+u.w*bmS[c+3];
      }
    }
    #pragma unroll
    for(int o=32;o>0;o>>=1) acc += __shfl_down(acc,o);
    if(lane==0) bcomb[d]=bs[d]+acc;
  }
  // bcat(960) + wcat(122880) + wib2(110592) + wihb(49152) + wmT(98304) = 381888
  for(int idx = blockIdx.x*256+tid; idx<381888; idx += gridDim.x*256){
    if(idx<960){
      int n=idx;
      float v;
      if(n<768) v=bm[n];
      else { int j=n-768; v = (j<64)? bh1[j] : (j<128)? bt1[j-64] : bv1[j-128]; }
      bcat[n]=v;
    } else if(idx<123840){
      int c=idx-960; int n=c>>7, k=c&127;
      float v;
      if(n<768) v=Wm[n*128+k];
      else if(n<832) v=Wh1[(n-768)*128+k];
      else if(n<896) v=Wt1[(n-832)*128+k];
      else v=Wv1[(n-896)*128+k];
      wcat[c]=f2b(v);
    } else if(idx<234432){
      int j=idx-123840; int r=j/768, k=j-r*768;
      float v = (r<128)? Wi[r*768+k] : (r<136)? ek[(r-128)*768+k] : 0.f;
      wib2[j]=f2b(v);
    } else if(idx<283584){
      int j=idx-234432;
      wihb[j]=f2b(Wih[j]);
    } else {
      int j=idx-283584; int s=j/768, d2=j-s*768;
      wmT[j]=f2b(Wm[d2*128+s]);
    }
  }
}

// ---------------- Wcomb via MFMA: C[d][e*128+s] = sum_d2 Ws[d][e*768+d2]*Wm[d2][s] ----------------
__global__ __launch_bounds__(256,2) void k_wcomb(const float* __restrict__ Ws, const u16* __restrict__ wmT,
                                                 u16* __restrict__ wcomb)
{
  __shared__ u16 AsU[128*104];
  __shared__ u16 BsU[128*104];
  char* AsB=(char*)AsU; char* BsB=(char*)BsU;
  int tid=threadIdx.x;
  int dt=blockIdx.x, e=blockIdx.y;
  int d0=dt*128;
  int w=tid>>6, L=tid&63, q4=L>>4, il=L&15;
  int msub=w*32;
  const f32x4 fz={0.f,0.f,0.f,0.f};
  f32x4 acc[2][8];
  #pragma unroll
  for(int tm=0;tm<2;tm++)
    #pragma unroll
    for(int tn=0;tn<8;tn++) acc[tm][tn]=fz;
  for(int kc=0;kc<8;kc++){
    __syncthreads();
    for(int it=0;it<12;it++){
      int slot=it*256+tid; int r=slot/24, c4=(slot-r*24)*4;
      float4 u=*reinterpret_cast<const float4*>(Ws + (size_t)(d0+r)*6144 + e*768 + kc*96 + c4);
      u16 v[4]={f2b(u.x),f2b(u.y),f2b(u.z),f2b(u.w)};
      uint2 p; __builtin_memcpy(&p,v,8);
      *reinterpret_cast<uint2*>(AsB + r*208 + c4*2) = p;
    }
    for(int it=0;it<6;it++){
      int slot=it*256+tid; int r=slot/12, o8=(slot-r*12)*8;
      uint4 u=*reinterpret_cast<const uint4*>(wmT + (size_t)r*768 + kc*96 + o8);
      *reinterpret_cast<uint4*>(BsB + r*208 + o8*2) = u;
    }
    __syncthreads();
    #pragma unroll
    for(int kt=0;kt<3;kt++){
      int kb=(kt*32+q4*8)*2;
      bf16x8 a0=__builtin_bit_cast(bf16x8,*reinterpret_cast<const uint4*>(AsB + (msub+il)*208 + kb));
      bf16x8 a1=__builtin_bit_cast(bf16x8,*reinterpret_cast<const uint4*>(AsB + (msub+16+il)*208 + kb));
      #pragma unroll
      for(int tn=0;tn<8;tn++){
        bf16x8 b=__builtin_bit_cast(bf16x8,*reinterpret_cast<const uint4*>(BsB + (tn*16+il)*208 + kb));
        acc[0][tn]=__builtin_amdgcn_mfma_f32_16x16x32_bf16(a0,b,acc[0][tn],0,0,0);
        acc[1][tn]=__builtin_amdgcn_mfma_f32_16x16x32_bf16(a1,b,acc[1][tn],0,0,0);
      }
    }
  }
  #pragma unroll
  for(int tm=0;tm<2;tm++){
    #pragma unroll
    for(int tn=0;tn<8;tn++){
      #pragma unroll
      for(int i=0;i<4;i++){
        int d=d0+msub+tm*16+q4*4+i;
        wcomb[d*1024 + e*128 + tn*16+il]=f2b(acc[tm][tn][i]);
      }
    }
  }
}

// ---------------- route v5b: MFMA GEMMs (proj+logits fused, q) + softmax + gpre emit ----------------
__global__ __launch_bounds__(256,2) void k_route(const float* __restrict__ hseq,
                                                 const u16* __restrict__ wib2, const u16* __restrict__ wihb,
                                                 const float* __restrict__ bi,
                                                 const float* __restrict__ bih, const float* __restrict__ bhh,
                                                 u16* __restrict__ gpre, float* __restrict__ out)
{
  __shared__ u16 AsU[16*768];     // 24,576 B; after q-phase aliased as qS f32[16][384]
  __shared__ u16 BsU[15360];      // 30,720 B: proj B 144x104u16; q B 384x40u16
  __shared__ u16 prS[16*128];     // proj bf16, swizzled (256B rows: in-bounds)
  __shared__ float lgs[16][8];
  __shared__ float wSm[16][8];
  __shared__ float biS[128];
  __shared__ float bS[384];
  char* AsB=(char*)AsU; char* BsB=(char*)BsU; char* prB=(char*)prS;
  int tid=threadIdx.x;
  int row0=blockIdx.x*16;
  // stage A (16x768)
  {
    int r=tid>>4, c0=(tid&15)*48;
    const float* src=hseq+(size_t)(row0+r)*768+c0;
    #pragma unroll
    for(int m=0;m<12;m++){
      float4 u=*reinterpret_cast<const float4*>(src+m*4);
      u16 v[4]={f2b(u.x),f2b(u.y),f2b(u.z),f2b(u.w)};
      uint2 p; __builtin_memcpy(&p,v,8);
      int k=c0+m*4;
      *reinterpret_cast<uint2*>(AsB + r*1536 + ((k*2)^SW(r))) = p;
    }
  }
  if(tid<32){ *reinterpret_cast<float4*>(&biS[tid*4]) = *reinterpret_cast<const float4*>(bi+tid*4); }
  if(tid>=64&&tid<160){
    int j4=(tid-64)*4;
    float4 u=*reinterpret_cast<const float4*>(bih+j4);
    if(j4<256){ float4 v=*reinterpret_cast<const float4*>(bhh+j4); u.x+=v.x;u.y+=v.y;u.z+=v.z;u.w+=v.w; }
    *reinterpret_cast<float4*>(&bS[j4])=u;
  }
  int w=tid>>6, L=tid&63, q4=L>>4, il=L&15;
  int ntP=(w==0)?3:2;
  f32x4 accP[3];
  #pragma unroll
  for(int i=0;i<3;i++) accP[i]=(f32x4){0.f,0.f,0.f,0.f};
  for(int kc=0;kc<8;kc++){
    __syncthreads();
    for(int it=0;it<7;it++){
      int slot=it*256+tid;
      if(slot<1728){
        int r=slot/12, o8=(slot-r*12)*8;
        uint4 u=*reinterpret_cast<const uint4*>(wib2 + (size_t)r*768 + kc*96 + o8);
        *reinterpret_cast<uint4*>(BsB + r*208 + o8*2) = u;
      }
    }
    __syncthreads();
    #pragma unroll
    for(int kt=0;kt<3;kt++){
      int k=kc*96+kt*32+q4*8;
      bf16x8 a=__builtin_bit_cast(bf16x8,*reinterpret_cast<const uint4*>(AsB + il*1536 + ((k*2)^SW(il))));
      int kb=(kt*32+q4*8)*2;
      #pragma unroll
      for(int t3=0;t3<3;t3++){
        if(t3<ntP){
          int col=(w+t3*4)*16+il;
          bf16x8 b=__builtin_bit_cast(bf16x8,*reinterpret_cast<const uint4*>(BsB + col*208 + kb));
          accP[t3]=__builtin_amdgcn_mfma_f32_16x16x32_bf16(a,b,accP[t3],0,0,0);
        }
      }
    }
  }
  #pragma unroll
  for(int t3=0;t3<3;t3++){
    if(t3<ntP){
      int tn=w+t3*4;
      #pragma unroll
      for(int i=0;i<4;i++){
        int r=q4*4+i;
        float v=accP[t3][i];
        if(tn<8){
          int col=tn*16+il;
          *reinterpret_cast<u16*>(prB + r*256 + ((col*2)^SW(r))) = f2b(v+biS[col]);
        } else if(il<8){
          lgs[r][il]=v*(1.0f/27.712812921102035f);
        }
      }
    }
  }
  __syncthreads();
  if(tid<16){
    int r=tid;
    float l[8],m=-1e30f;
    #pragma unroll
    for(int e=0;e<8;e++){ l[e]=lgs[r][e]; m=fmaxf(m,l[e]); }
    float s=0.f;
    #pragma unroll
    for(int e=0;e<8;e++){ l[e]=__builtin_amdgcn_exp2f(1.4426950408889634f*(l[e]-m)); s+=l[e]; }
    float inv=__builtin_amdgcn_rcpf(s);
    #pragma unroll
    for(int e=0;e<8;e++){ float wv=l[e]*inv; wSm[r][e]=wv; out[OUT_ROUTE+(row0+r)*8+e]=wv; }
  }
  f32x4 accQ[6];
  #pragma unroll
  for(int i=0;i<6;i++) accQ[i]=(f32x4){0.f,0.f,0.f,0.f};
  for(int kt=0;kt<4;kt++){
    __syncthreads();
    for(int it=0;it<6;it++){
      int slot=it*256+tid;
      int r=slot>>2, qt=slot&3;
      uint4 u=*reinterpret_cast<const uint4*>(wihb + (size_t)r*128 + kt*32 + qt*8);
      *reinterpret_cast<uint4*>(BsB + r*80 + qt*16) = u;
    }
    __syncthreads();
    int kb=(kt*32+q4*8)*2;
    bf16x8 a=__builtin_bit_cast(bf16x8,*reinterpret_cast<const uint4*>(prB + il*256 + (kb^SW(il))));
    #pragma unroll
    for(int t6=0;t6<6;t6++){
      int col=(w+t6*4)*16+il;
      bf16x8 b=__builtin_bit_cast(bf16x8,*reinterpret_cast<const uint4*>(BsB + col*80 + q4*16));
      accQ[t6]=__builtin_amdgcn_mfma_f32_16x16x32_bf16(a,b,accQ[t6],0,0,0);
    }
  }
  float* qS=(float*)AsU;
  #pragma unroll
  for(int t6=0;t6<6;t6++){
    int col=(w+t6*4)*16+il;
    #pragma unroll
    for(int i=0;i<4;i++) qS[(q4*4+i)*384+col]=accQ[t6][i];
  }
  __syncthreads();
  {
    int ch=tid&127, hh=tid>>7;
    float b0=bS[ch], b1=bS[128+ch], b2=bS[256+ch];
    #pragma unroll 1
    for(int r=0;r<16;r++){
      float q0=qS[r*384+ch], q1=qS[r*384+128+ch], q2=qS[r*384+256+ch];
      u16* dst=gpre+(size_t)(row0+r)*4096;
      #pragma unroll
      for(int j=0;j<4;j++){
        int e=(hh+j*2)&7;
        float wv=wSm[r][e];
        u16 ov[4]={f2b(wv*q0+b0),f2b(wv*q1+b1),f2b(wv*q2+b2),0};
        uint2 o; __builtin_memcpy(&o,ov,8);
        *reinterpret_cast<uint2*>(dst + (e*128+ch)*4)=o;
      }
    }
  }
}

// ---------------- sequential GRU scan v4: 16 blocks x 256 threads, 2 cells/lane ----------------
// LDS-convoy reduction: 8 waves x 4 ds_read_b128 (32 instrs/CU/step, ~384 cyc pipe) was the
// dominant per-step cost. 4 waves x 4 reads halves it; each lane computes 2 cells
// (ch, ch+64) of its chain q4; B-frags double (24 bf16x8, persistent). 6 independent
// MFMA acc chains remove dep stalls. f32 OUT_STATE stores fused (k_expand deleted).
#define SCAN_SYNC asm volatile("s_waitcnt lgkmcnt(0)\n\ts_barrier" ::: "memory")

#define SCAN_STEP(BUF,NXT,P,DOLOAD)                                                         \
  {                                                                                         \
    bf16x8 af[4];                                                                           \
    _Pragma("unroll")                                                                       \
    for(int kt=0;kt<4;kt++)                                                                 \
      af[kt]=__builtin_bit_cast(bf16x8, *reinterpret_cast<const uint4*>(&hbf[BUF][il>>2][kt*32+q4*8])); \
    u16 cwa[4], cwb[4];                                                                     \
    __builtin_memcpy(cwa,&gva[P],8);                                                        \
    __builtin_memcpy(cwb,&gvb[P],8);                                                        \
    if(DOLOAD){                                                                             \
      gva[P]=*reinterpret_cast<const uint2*>(gp);                                           \
      gvb[P]=*reinterpret_cast<const uint2*>(gp+256);                                       \
      gp+=4096;                                                                             \
    }                                                                                       \
    f32x4 ac[2][3];                                                                         \
    _Pragma("unroll")                                                                       \
    for(int cg=0;cg<2;cg++){                                                                \
      _Pragma("unroll")                                                                     \
      for(int g=0;g<3;g++) ac[cg][g]=(f32x4){0.f,0.f,0.f,0.f};                              \
    }                                                                                       \
    _Pragma("unroll")                                                                       \
    for(int kt=0;kt<4;kt++){                                                                \
      _Pragma("unroll")                                                                     \
      for(int cg=0;cg<2;cg++){                                                              \
        _Pragma("unroll")                                                                   \
        for(int g=0;g<3;g++)                                                                \
          ac[cg][g]=__builtin_amdgcn_mfma_f32_16x16x32_bf16(af[kt],bfr[cg][g][kt],ac[cg][g],0,0,0); \
      }                                                                                     \
    }                                                                                       \
    {                                                                                       \
      float r0=sigf(ac[0][0][0]+b2f(cwa[0]));                                               \
      float z0=sigf(ac[0][1][0]+b2f(cwa[1]));                                               \
      float n0=tanh_(b2f(cwa[2])+r0*(ac[0][2][0]+bhhn0));                                   \
      float h0=n0+z0*(hp0-n0);  hp0=h0;                                                     \
      float r1=sigf(ac[1][0][0]+b2f(cwb[0]));                                               \
      float z1=sigf(ac[1][1][0]+b2f(cwb[1]));                                               \
      float n1=tanh_(b2f(cwb[2])+r1*(ac[1][2][0]+bhhn1));                                   \
      float h1=n1+z1*(hp1-n1);  hp1=h1;                                                     \
      u16 hb0=f2b(h0), hb1=f2b(h1);                                                         \
      hbf[NXT][q4][ch0]=hb0;                                                                \
      hbf[NXT][q4][ch1]=hb1;                                                                \
      sbase[0]=hb0; sbase[64]=hb1;                                                          \
      obase[0]=h0;  obase[64]=h1;                                                           \
    }                                                                                       \
    sbase += 1024; obase += 1024;                                                           \
    SCAN_SYNC;                                                                              \
  }

__global__ __launch_bounds__(256,1) void k_scan(const float* __restrict__ Whh, const float* __restrict__ bhh,
                                                const float* __restrict__ state0,
                                                const u16* __restrict__ gpre, u16* __restrict__ shadow,
                                                float* __restrict__ outstate)
{
  __shared__ u16 hbf[2][4][144];
  int tid=threadIdx.x;
  int w=tid>>6, L=tid&63, q4=L>>4, il=L&15;
  int blk=blockIdx.x;
  int b=blk>>1, e0=(blk&1)*4;
  int ch0=w*16+il, ch1=64+ch0;
  // persistent B-fragments of W_hh for both ch-groups x 3 gates x 4 k-tiles
  bf16x8 bfr[2][3][4];
  #pragma unroll
  for(int cg=0; cg<2; cg++){
    #pragma unroll
    for(int g=0; g<3; g++){
      #pragma unroll
      for(int kt=0; kt<4; kt++){
        u16 t[8];
        #pragma unroll
        for(int j=0;j<8;j++)
          t[j]=f2b(Whh[(size_t)(g*128 + cg*64 + ch0)*128 + kt*32 + q4*8 + j]);
        __builtin_memcpy(&bfr[cg][g][kt],t,16);
      }
    }
  }
  float bhhn0 = bhh[256+ch0], bhhn1 = bhh[256+ch1];
  float hp0 = state0[(e0+q4)*128+ch0], hp1 = state0[(e0+q4)*128+ch1];
  for(int idx=tid; idx<512; idx+=256){
    int m=idx>>7, c=idx&127;
    hbf[0][m][c]=f2b(state0[(e0+m)*128+c]);
  }
  const u16* gp = gpre + (size_t)b*1024*4096 + ((e0+q4)*128+ch0)*4;
  u16* sbase = shadow + ((size_t)b*8192 + (e0+q4))*128 + ch0;
  float* obase = outstate + ((size_t)b*8192 + (e0+q4))*128 + ch0;
  uint2 gva[4], gvb[4];
  #pragma unroll
  for(int p=0;p<4;p++){
    gva[p]=*reinterpret_cast<const uint2*>(gp);
    gvb[p]=*reinterpret_cast<const uint2*>(gp+256);
    gp+=4096;
  }
  SCAN_SYNC;
  #pragma unroll 1
  for(int t2=0;t2<255;t2++){
    SCAN_STEP(0,1,0,1)
    SCAN_STEP(1,0,1,1)
    SCAN_STEP(0,1,2,1)
    SCAN_STEP(1,0,3,1)
  }
  SCAN_STEP(0,1,0,0)
  SCAN_STEP(1,0,1,0)
  SCAN_STEP(0,1,2,0)
  SCAN_STEP(1,0,3,0)
}

// ---------------- memory_stack + head hidden (GEMM [65536x128]@[128x960]) ----------------
__global__ __launch_bounds__(256) void k_mem(const u16* __restrict__ state, const u16* __restrict__ wcat,
                                             const float* __restrict__ bcat,
                                             float* __restrict__ memout, u16* __restrict__ hdn)
{
  __shared__ u16 As[128][136];
  __shared__ u16 Bs[96][136];
  int tid=threadIdx.x;
  int bx=blockIdx.x, ny=blockIdx.y;
  for(int it=0;it<8;it++){
    int v=it*256+tid; int r=v>>4, c8=(v&15)*8;
    *reinterpret_cast<uint4*>(&As[r][c8]) = *reinterpret_cast<const uint4*>(state + (bx*128+r)*128 + c8);
  }
  for(int it=0;it<6;it++){
    int v=it*256+tid; int r=v>>4, c8=(v&15)*8;
    *reinterpret_cast<uint4*>(&Bs[r][c8]) = *reinterpret_cast<const uint4*>(wcat + (ny*96+r)*128 + c8);
  }
  __syncthreads();
  int w=tid>>6, L=tid&63, q4=L>>4, il=L&15;
  int msub=w*32;
  bf16x8 af[2][4];
  #pragma unroll
  for(int tm=0;tm<2;tm++)
    #pragma unroll
    for(int kt=0;kt<4;kt++)
      af[tm][kt]=__builtin_bit_cast(bf16x8,*reinterpret_cast<const uint4*>(&As[msub+tm*16+il][kt*32+q4*8]));
  const f32x4 fz = {0.f,0.f,0.f,0.f};
  f32x4 acc[2][6];
  #pragma unroll
  for(int tm=0;tm<2;tm++){
    #pragma unroll
    for(int tn=0;tn<6;tn++) acc[tm][tn]=fz;
  }
  #pragma unroll
  for(int tn=0;tn<6;tn++){
    bf16x8 bf[4];
    #pragma unroll
    for(int kt=0;kt<4;kt++)
      bf[kt]=__builtin_bit_cast(bf16x8,*reinterpret_cast<const uint4*>(&Bs[tn*16+il][kt*32+q4*8]));
    #pragma unroll
    for(int tm=0;tm<2;tm++){
      #pragma unroll
      for(int kt=0;kt<4;kt++)
        acc[tm][tn]=__builtin_amdgcn_mfma_f32_16x16x32_bf16(af[tm][kt],bf[kt],acc[tm][tn],0,0,0);
    }
  }
  #pragma unroll
  for(int tm=0;tm<2;tm++){
    #pragma unroll
    for(int tn=0;tn<6;tn++){
      int col=ny*96+tn*16+il;
      float bias=bcat[col];
      #pragma unroll
      for(int i=0;i<4;i++){
        int row=bx*128+msub+tm*16+q4*4+i;
        float val=acc[tm][tn][i]+bias;
        if(ny<8) memout[row*768+col]=val;
        else hdn[row*192+(col-768)]=f2b(geluf(val));
      }
    }
  }
}

// ---------------- pooled = state_flat[8192x1024] @ Wcomb.T + b_comb ----------------
__global__ __launch_bounds__(256) void k_pool(const u16* __restrict__ state, const u16* __restrict__ wcomb,
                                              const float* __restrict__ bcomb, float* __restrict__ pooled)
{
  __shared__ u16 As[128][136];
  __shared__ u16 Bs[96][136];
  int tid=threadIdx.x;
  int bx=blockIdx.x, ny=blockIdx.y;
  int w=tid>>6, L=tid&63, q4=L>>4, il=L&15;
  int msub=w*32;
  const f32x4 fz = {0.f,0.f,0.f,0.f};
  f32x4 acc[2][6];
  #pragma unroll
  for(int tm=0;tm<2;tm++){
    #pragma unroll
    for(int tn=0;tn<6;tn++) acc[tm][tn]=fz;
  }
  for(int kc=0;kc<8;kc++){
    __syncthreads();
    for(int it=0;it<8;it++){
      int v=it*256+tid; int r=v>>4, c8=(v&15)*8;
      *reinterpret_cast<uint4*>(&As[r][c8]) = *reinterpret_cast<const uint4*>(state + (bx*128+r)*1024 + kc*128 + c8);
    }
    for(int it=0;it<6;it++){
      int v=it*256+tid; int r=v>>4, c8=(v&15)*8;
      *reinterpret_cast<uint4*>(&Bs[r][c8]) = *reinterpret_cast<const uint4*>(wcomb + (ny*96+r)*1024 + kc*128 + c8);
    }
    __syncthreads();
    bf16x8 af[2][4];
    #pragma unroll
    for(int tm=0;tm<2;tm++)
      #pragma unroll
      for(int kt=0;kt<4;kt++)
        af[tm][kt]=__builtin_bit_cast(bf16x8,*reinterpret_cast<const uint4*>(&As[msub+tm*16+il][kt*32+q4*8]));
    #pragma unroll
    for(int tn=0;tn<6;tn++){
      bf16x8 bf[4];
      #pragma unroll
      for(int kt=0;kt<4;kt++)
        bf[kt]=__builtin_bit_cast(bf16x8,*reinterpret_cast<const uint4*>(&Bs[tn*16+il][kt*32+q4*8]));
      #pragma unroll
      for(int tm=0;tm<2;tm++){
        #pragma unroll
        for(int kt=0;kt<4;kt++)
          acc[tm][tn]=__builtin_amdgcn_mfma_f32_16x16x32_bf16(af[tm][kt],bf[kt],acc[tm][tn],0,0,0);
      }
    }
  }
  #pragma unroll
  for(int tm=0;tm<2;tm++){
    #pragma unroll
    for(int tn=0;tn<6;tn++){
      int col=ny*96+tn*16+il;
      float bias=bcomb[col];
      #pragma unroll
      for(int i=0;i<4;i++){
        int row=bx*128+msub+tm*16+q4*4+i;
        pooled[row*768+col]=acc[tm][tn][i]+bias;
      }
    }
  }
}

// ---------------- head second layer ----------------
__global__ __launch_bounds__(256) void k_heads(const u16* __restrict__ hdn,
                                               const float* __restrict__ Wh2, const float* __restrict__ bh2,
                                               const float* __restrict__ Wt2, const float* __restrict__ bt2,
                                               const float* __restrict__ Wv2, const float* __restrict__ bv2,
                                               float* __restrict__ out)
{
  int oid=blockIdx.x*256+threadIdx.x;
  int row=oid&65535, head=oid>>16;
  const float* w2 = (head==0)?Wh2:(head==1)?Wt2:Wv2;
  float b2 = ((head==0)?bh2:(head==1)?bt2:bv2)[0];
  float acc=0.f;
  const u16* src = hdn + row*192 + head*64;
  for(int j0=0;j0<64;j0+=8){
    uint4 hu=*reinterpret_cast<const uint4*>(src+j0);
    u16 hs[8]; __builtin_memcpy(hs,&hu,16);
    #pragma unroll
    for(int j=0;j<8;j++) acc+=b2f(hs[j])*w2[j0+j];
  }
  out[OUT_HOLD + head*65536 + row]=acc+b2;
}

extern "C" void kernel_launch(void* const* d_in, const int* in_sizes, int n_in,
                              void* d_out, int out_size, void* d_ws, size_t ws_size,
                              hipStream_t stream)
{
  const float* hseq=(const float*)d_in[0];
  const float* ek  =(const float*)d_in[1];
  const float* st0 =(const float*)d_in[2];
  const float* Wi  =(const float*)d_in[3];
  const float* bi  =(const float*)d_in[4];
  const float* Wih =(const float*)d_in[5];
  const float* Whh =(const float*)d_in[6];
  const float* bih =(const float*)d_in[7];
  const float* bhh =(const float*)d_in[8];
  const float* Wm  =(const float*)d_in[9];
  const float* bm  =(const float*)d_in[10];
  const float* Ws  =(const float*)d_in[11];
  const float* bs  =(const float*)d_in[12];
  const float* Wh1 =(const float*)d_in[13];
  const float* bh1 =(const float*)d_in[14];
  const float* Wh2 =(const float*)d_in[15];
  const float* bh2 =(const float*)d_in[16];
  const float* Wt1 =(const float*)d_in[17];
  const float* bt1 =(const float*)d_in[18];
  const float* Wt2 =(const float*)d_in[19];
  const float* bt2 =(const float*)d_in[20];
  const float* Wv1 =(const float*)d_in[21];
  const float* bv1 =(const float*)d_in[22];
  const float* Wv2 =(const float*)d_in[23];
  const float* bv2 =(const float*)d_in[24];
  float* out=(float*)d_out;
  char* ws=(char*)d_ws;
  // layout v6 (peak ~86.3 MB):
  u16*  gpre  =(u16*)ws;                   // [0, 67,108,864)  64 MB, dead after k_scan
  u16*  wcomb =(u16*)(ws+67108864);        // 1,572,864 -> 68,681,728
  float* bcomb=(float*)(ws+68681728);      // 3,072     -> 68,684,800
  u16*  wcat  =(u16*)(ws+68684800);        // 245,760   -> 68,930,560
  float* bcat =(float*)(ws+68930560);      // 3,840     -> 68,934,400
  u16*  shadow=(u16*)(ws+68934400);        // 16,777,216 -> 85,711,616
  u16*  wib2  =(u16*)(ws+85711616);        // 221,184   -> 85,932,800
  u16*  wihb  =(u16*)(ws+85932800);        // 98,304    -> 86,031,104
  u16*  wmT   =(u16*)(ws+86031104);        // 196,608   -> 86,227,712
  u16*  hdn   =(u16*)ws;                   // 25 MB, OVERLAPS dead gpre (k_mem runs after k_scan)

  hipLaunchKernelGGL(k_prep, dim3(192), dim3(256), 0, stream,
                     Ws,bs,bm,Wm,Wh1,bh1,Wt1,bt1,Wv1,bv1,Wi,ek,Wih,wcat,bcat,bcomb,wib2,wihb,wmT);
  hipLaunchKernelGGL(k_wcomb, dim3(6,8), dim3(256), 0, stream, Ws,wmT,wcomb);
  hipLaunchKernelGGL(k_route, dim3(512), dim3(256), 0, stream, hseq,wib2,wihb,bi,bih,bhh,gpre,out);
  hipLaunchKernelGGL(k_scan, dim3(16), dim3(256), 0, stream, Whh,bhh,st0,gpre,shadow,out+OUT_STATE);
  hipLaunchKernelGGL(k_mem, dim3(512,10), dim3(256), 0, stream, shadow,wcat,bcat,out+OUT_MEM,hdn);
  hipLaunchKernelGGL(k_pool, dim3(64,8), dim3(256), 0, stream, shadow,wcomb,bcomb,out+OUT_POOLED);
  hipLaunchKernelGGL(k_heads, dim3(768), dim3(256), 0, stream, hdn,Wh2,bh2,Wt2,bt2,Wv2,bv2,out);
}